// Round 3
// baseline (187.190 us; speedup 1.0000x reference)
//
#include <hip/hip_runtime.h>
#include <math.h>

#define BB   32
#define CC   512
#define NPIX 1600
#define KK   64
#define NT   25        // 64-wide n-tiles
#define EPSF 1e-12f

__device__ __forceinline__ void gl_lds16(const float* g, float* l) {
    __builtin_amdgcn_global_load_lds(
        (const __attribute__((address_space(1))) void*)g,
        (__attribute__((address_space(3))) void*)l, 16, 0, 0);
}

// ---------------------------------------------------------------------------
// k_wt: Wt[c][k] = w[k][c]   (one-time 128KB transpose, LDS-tiled)
// ---------------------------------------------------------------------------
__global__ __launch_bounds__(256) void k_wt(const float* __restrict__ w,
                                            float* __restrict__ wt) {
    __shared__ float tileS[64][65];
    int c0 = blockIdx.x * 64;
    int t = threadIdx.x;
    int kk = t >> 4, c4 = (t & 15) * 4;
#pragma unroll
    for (int i = 0; i < 4; ++i) {
        float4 v = *(const float4*)&w[(size_t)(kk + i * 16) * CC + c0 + c4];
        tileS[kk + i * 16][c4]     = v.x;
        tileS[kk + i * 16][c4 + 1] = v.y;
        tileS[kk + i * 16][c4 + 2] = v.z;
        tileS[kk + i * 16][c4 + 3] = v.w;
    }
    __syncthreads();
    int cc = t >> 2, kq = (t & 3) * 4;
#pragma unroll
    for (int i = 0; i < 4; ++i) {
        int k = kq + i * 16;
        *(float4*)&wt[(size_t)(c0 + cc) * KK + k] =
            make_float4(tileS[k][cc], tileS[k + 1][cc],
                        tileS[k + 2][cc], tileS[k + 3][cc]);
    }
}

// ---------------------------------------------------------------------------
// k_gemm1: lp[half][b][k][n] = sum_{c in half} w[k,c] x[b,c,n]  (unscaled)
//          ssq_p[b][half][n] = sum_{c in half} x^2
// grid (25 n-tiles, 2 c-halves, 32 b) = 1600 blocks, 256 thr.
// Double-buffered: W via global_load_lds (from Wt), X reg-staged (feeds ssq).
// ---------------------------------------------------------------------------
__global__ __launch_bounds__(256) void k_gemm1(const float* __restrict__ x,
                                               const float* __restrict__ wt,
                                               float* __restrict__ lp,
                                               float* __restrict__ ssq_p) {
    int tile = blockIdx.x;
    int half = blockIdx.y;
    int b    = blockIdx.z;
    int n0 = tile * 64;
    int cbase = half * 256;
    __shared__ __align__(16) float Xs[2][32 * 64];
    __shared__ __align__(16) float Ws[2][32 * 64];
    __shared__ __align__(16) float red[16 * 64];
    int t = threadIdx.x;
    int tn = t & 15, tg = t >> 4;
    int lane = t & 63, wv = t >> 6;
    const float* xb = x + (size_t)b * CC * NPIX + n0;
    float acc[4][4] = {};
    float ss[4] = {};
    int srow = t >> 4;            // X-staging row (and +16)
    int sn   = (t & 15) * 4;      // X-staging col group
    int wrl  = lane >> 4;         // W glds lane row
    int wcl  = (lane & 15) * 4;   // W glds lane col

    // prologue: stage c-block 0 into buffer 0
    {
#pragma unroll
        for (int i = 0; i < 2; ++i) {
            int r = wv * 8 + i * 4;
            gl_lds16(&wt[(size_t)(cbase + r + wrl) * KK + wcl], &Ws[0][r * 64]);
        }
        float4 xv0 = *(const float4*)&xb[(size_t)(cbase + srow) * NPIX + sn];
        float4 xv1 = *(const float4*)&xb[(size_t)(cbase + srow + 16) * NPIX + sn];
        ss[0] = fmaf(xv0.x, xv0.x, xv1.x * xv1.x);
        ss[1] = fmaf(xv0.y, xv0.y, xv1.y * xv1.y);
        ss[2] = fmaf(xv0.z, xv0.z, xv1.z * xv1.z);
        ss[3] = fmaf(xv0.w, xv0.w, xv1.w * xv1.w);
        *(float4*)&Xs[0][srow * 64 + sn]        = xv0;
        *(float4*)&Xs[0][(srow + 16) * 64 + sn] = xv1;
    }
    __syncthreads();

    int cur = 0;
    for (int it = 0; it < 8; ++it) {
        float4 xv0, xv1;
        bool pre = (it < 7);
        if (pre) {
            int cg = cbase + (it + 1) * 32;
#pragma unroll
            for (int i = 0; i < 2; ++i) {
                int r = wv * 8 + i * 4;
                gl_lds16(&wt[(size_t)(cg + r + wrl) * KK + wcl], &Ws[cur ^ 1][r * 64]);
            }
            xv0 = *(const float4*)&xb[(size_t)(cg + srow) * NPIX + sn];
            xv1 = *(const float4*)&xb[(size_t)(cg + srow + 16) * NPIX + sn];
        }
        const float* Xc = &Xs[cur][0];
        const float* Wc = &Ws[cur][0];
#pragma unroll
        for (int cc = 0; cc < 32; ++cc) {
            float4 wv4 = *(const float4*)&Wc[cc * 64 + tg * 4];
            float4 xv4 = *(const float4*)&Xc[cc * 64 + tn * 4];
            float wa[4] = {wv4.x, wv4.y, wv4.z, wv4.w};
            float xa[4] = {xv4.x, xv4.y, xv4.z, xv4.w};
#pragma unroll
            for (int i = 0; i < 4; ++i)
#pragma unroll
                for (int j = 0; j < 4; ++j)
                    acc[i][j] = fmaf(wa[i], xa[j], acc[i][j]);
        }
        if (pre) {
            ss[0] = fmaf(xv0.x, xv0.x, fmaf(xv1.x, xv1.x, ss[0]));
            ss[1] = fmaf(xv0.y, xv0.y, fmaf(xv1.y, xv1.y, ss[1]));
            ss[2] = fmaf(xv0.z, xv0.z, fmaf(xv1.z, xv1.z, ss[2]));
            ss[3] = fmaf(xv0.w, xv0.w, fmaf(xv1.w, xv1.w, ss[3]));
            *(float4*)&Xs[cur ^ 1][srow * 64 + sn]        = xv0;
            *(float4*)&Xs[cur ^ 1][(srow + 16) * 64 + sn] = xv1;
        }
        __syncthreads();
        cur ^= 1;
    }

    // logits partial out (unscaled)
#pragma unroll
    for (int i = 0; i < 4; ++i) {
        int k = tg * 4 + i;
        *(float4*)&lp[(((size_t)half * BB + b) * KK + k) * NPIX + n0 + tn * 4] =
            make_float4(acc[i][0], acc[i][1], acc[i][2], acc[i][3]);
    }
    // ssq partial: reduce 16 staging groups per column
    *(float4*)&red[srow * 64 + sn] = make_float4(ss[0], ss[1], ss[2], ss[3]);
    __syncthreads();
#pragma unroll
    for (int off = 8; off >= 1; off >>= 1) {
        if (srow < off) {
#pragma unroll
            for (int j = 0; j < 4; ++j)
                red[srow * 64 + sn + j] += red[(srow + off) * 64 + sn + j];
        }
        __syncthreads();
    }
    if (t < 16) {
        float4 v = *(float4*)&red[t * 4];
        *(float4*)&ssq_p[((size_t)b * 2 + half) * NPIX + n0 + t * 4] = v;
    }
}

// ---------------------------------------------------------------------------
// k_smax: combine halves, scale by invn, softmax over k, write a_t[b][n][k],
// invn, asum_p.  grid (25, 32), 256 thr.
// ---------------------------------------------------------------------------
__global__ __launch_bounds__(256) void k_smax(const float* __restrict__ lp,
                                              const float* __restrict__ ssq_p,
                                              float* __restrict__ a_t,
                                              float* __restrict__ invn,
                                              float* __restrict__ asum_p) {
    int tile = blockIdx.x, b = blockIdx.y;
    int n0 = tile * 64;
    __shared__ __align__(16) float red[16 * 64];
    int t = threadIdx.x, tn = t & 15, tg = t >> 4;

    float iv[4];
    {
        float4 s0 = *(const float4*)&ssq_p[((size_t)b * 2 + 0) * NPIX + n0 + tn * 4];
        float4 s1 = *(const float4*)&ssq_p[((size_t)b * 2 + 1) * NPIX + n0 + tn * 4];
        iv[0] = 1.f / fmaxf(sqrtf(s0.x + s1.x), EPSF);
        iv[1] = 1.f / fmaxf(sqrtf(s0.y + s1.y), EPSF);
        iv[2] = 1.f / fmaxf(sqrtf(s0.z + s1.z), EPSF);
        iv[3] = 1.f / fmaxf(sqrtf(s0.w + s1.w), EPSF);
    }
    if (tg == 0)
        *(float4*)&invn[b * NPIX + n0 + tn * 4] = make_float4(iv[0], iv[1], iv[2], iv[3]);

    float l[4][4], lm[4];
#pragma unroll
    for (int i = 0; i < 4; ++i) {
        int k = tg * 4 + i;
        float4 v0 = *(const float4*)&lp[((size_t)b * KK + k) * NPIX + n0 + tn * 4];
        float4 v1 = *(const float4*)&lp[(((size_t)BB + b) * KK + k) * NPIX + n0 + tn * 4];
        l[i][0] = (v0.x + v1.x) * iv[0];
        l[i][1] = (v0.y + v1.y) * iv[1];
        l[i][2] = (v0.z + v1.z) * iv[2];
        l[i][3] = (v0.w + v1.w) * iv[3];
    }
#pragma unroll
    for (int j = 0; j < 4; ++j)
        lm[j] = fmaxf(fmaxf(l[0][j], l[1][j]), fmaxf(l[2][j], l[3][j]));
    *(float4*)&red[tg * 64 + tn * 4] = make_float4(lm[0], lm[1], lm[2], lm[3]);
    __syncthreads();
#pragma unroll
    for (int off = 8; off >= 1; off >>= 1) {
        if (tg < off) {
#pragma unroll
            for (int j = 0; j < 4; ++j) {
                int idx = tg * 64 + tn * 4 + j;
                red[idx] = fmaxf(red[idx], red[(tg + off) * 64 + tn * 4 + j]);
            }
        }
        __syncthreads();
    }
    float m[4];
#pragma unroll
    for (int j = 0; j < 4; ++j) m[j] = red[tn * 4 + j];
    __syncthreads();

    float e[4][4], ls[4];
#pragma unroll
    for (int j = 0; j < 4; ++j) {
        ls[j] = 0.f;
#pragma unroll
        for (int i = 0; i < 4; ++i) {
            e[i][j] = expf(l[i][j] - m[j]);
            ls[j] += e[i][j];
        }
    }
    *(float4*)&red[tg * 64 + tn * 4] = make_float4(ls[0], ls[1], ls[2], ls[3]);
    __syncthreads();
#pragma unroll
    for (int off = 8; off >= 1; off >>= 1) {
        if (tg < off) {
#pragma unroll
            for (int j = 0; j < 4; ++j) {
                int idx = tg * 64 + tn * 4 + j;
                red[idx] += red[(tg + off) * 64 + tn * 4 + j];
            }
        }
        __syncthreads();
    }

    float p[4] = {};
#pragma unroll
    for (int j = 0; j < 4; ++j) {
        float sd = 1.f / red[tn * 4 + j];
        float4 o = make_float4(e[0][j] * sd, e[1][j] * sd, e[2][j] * sd, e[3][j] * sd);
        *(float4*)&a_t[((size_t)b * NPIX + n0 + tn * 4 + j) * KK + tg * 4] = o;
        p[0] += o.x; p[1] += o.y; p[2] += o.z; p[3] += o.w;
    }
#pragma unroll
    for (int off = 1; off < 16; off <<= 1) {
#pragma unroll
        for (int i = 0; i < 4; ++i) p[i] += __shfl_xor(p[i], off, 64);
    }
    if (tn == 0) {
#pragma unroll
        for (int i = 0; i < 4; ++i)
            asum_p[((size_t)b * KK + tg * 4 + i) * NT + tile] = p[i];
    }
}

// ---------------------------------------------------------------------------
// k_vlad: part[s][b][k][c] = sum_{n in chunk s} a[k,n] invn[n] x[c,n]
// grid (4 c-tiles x128, ns, 32 b), 256 thr, double-buffered, As via
// global_load_lds, Xs XOR-swizzled register transpose.
// ---------------------------------------------------------------------------
__global__ __launch_bounds__(256) void k_vlad(const float* __restrict__ a_t,
                                              const float* __restrict__ x,
                                              const float* __restrict__ invn,
                                              float* __restrict__ part,
                                              int nchunk) {
    int c0 = blockIdx.x * 128;
    int s  = blockIdx.y;
    int b  = blockIdx.z;
    __shared__ __align__(16) float As[2][32 * 64];
    __shared__ __align__(16) float Xs[2][32 * 128];
    int t = threadIdx.x;
    int tc = t & 31, tg = t >> 5;
    int lane = t & 63, wv = t >> 6;
    float acc[8][4] = {};
    const float* ab  = a_t + (size_t)b * NPIX * KK;
    const float* xb  = x + (size_t)b * CC * NPIX;
    const float* ivb = invn + b * NPIX;
    int nbase = s * nchunk;
    int niters = nchunk / 32;
    int arl = lane >> 4;            // As glds lane row
    int acl = (lane & 15) * 4;      // As glds lane col
    int n4  = t & 7;                // X-staging col group
    int scc = t >> 3;               // X-staging row offset (+32i)
    int swz = n4 << 2;

    // prologue: stage chunk-iter 0 into buffer 0
    {
#pragma unroll
        for (int i = 0; i < 2; ++i) {
            int r = wv * 8 + i * 4;
            gl_lds16(&ab[(size_t)(nbase + r + arl) * KK + acl], &As[0][r * 64]);
        }
        float4 iv4 = *(const float4*)&ivb[nbase + n4 * 4];
        float ivr[4] = {iv4.x, iv4.y, iv4.z, iv4.w};
#pragma unroll
        for (int i = 0; i < 4; ++i) {
            int cc = i * 32 + scc;
            float4 xv = *(const float4*)&xb[(size_t)(c0 + cc) * NPIX + nbase + n4 * 4];
            int cs = cc ^ swz;
            Xs[0][(n4 * 4 + 0) * 128 + cs] = xv.x * ivr[0];
            Xs[0][(n4 * 4 + 1) * 128 + cs] = xv.y * ivr[1];
            Xs[0][(n4 * 4 + 2) * 128 + cs] = xv.z * ivr[2];
            Xs[0][(n4 * 4 + 3) * 128 + cs] = xv.w * ivr[3];
        }
    }
    __syncthreads();

    int cur = 0;
    for (int it = 0; it < niters; ++it) {
        bool pre = (it + 1 < niters);
        int n0g = nbase + (it + 1) * 32;
        float4 xv[4];
        float ivr[4];
        if (pre) {
#pragma unroll
            for (int i = 0; i < 2; ++i) {
                int r = wv * 8 + i * 4;
                gl_lds16(&ab[(size_t)(n0g + r + arl) * KK + acl], &As[cur ^ 1][r * 64]);
            }
            float4 iv4 = *(const float4*)&ivb[n0g + n4 * 4];
            ivr[0] = iv4.x; ivr[1] = iv4.y; ivr[2] = iv4.z; ivr[3] = iv4.w;
#pragma unroll
            for (int i = 0; i < 4; ++i) {
                int cc = i * 32 + scc;
                xv[i] = *(const float4*)&xb[(size_t)(c0 + cc) * NPIX + n0g + n4 * 4];
            }
        }
        const float* Ac = &As[cur][0];
        const float* Xc = &Xs[cur][0];
#pragma unroll
        for (int nn = 0; nn < 32; ++nn) {
            float4 a0 = *(const float4*)&Ac[nn * 64 + tg * 8];
            float4 a1 = *(const float4*)&Ac[nn * 64 + tg * 8 + 4];
            float4 xv4 = *(const float4*)&Xc[nn * 128 + ((tc * 4) ^ ((nn >> 2) << 2))];
            float aa[8] = {a0.x, a0.y, a0.z, a0.w, a1.x, a1.y, a1.z, a1.w};
            float xa[4] = {xv4.x, xv4.y, xv4.z, xv4.w};
#pragma unroll
            for (int i = 0; i < 8; ++i)
#pragma unroll
                for (int j = 0; j < 4; ++j)
                    acc[i][j] = fmaf(aa[i], xa[j], acc[i][j]);
        }
        if (pre) {
#pragma unroll
            for (int i = 0; i < 4; ++i) {
                int cc = i * 32 + scc;
                int cs = cc ^ swz;
                Xs[cur ^ 1][(n4 * 4 + 0) * 128 + cs] = xv[i].x * ivr[0];
                Xs[cur ^ 1][(n4 * 4 + 1) * 128 + cs] = xv[i].y * ivr[1];
                Xs[cur ^ 1][(n4 * 4 + 2) * 128 + cs] = xv[i].z * ivr[2];
                Xs[cur ^ 1][(n4 * 4 + 3) * 128 + cs] = xv[i].w * ivr[3];
            }
        }
        __syncthreads();
        cur ^= 1;
    }
#pragma unroll
    for (int i = 0; i < 8; ++i) {
        int k = tg * 8 + i;
        *(float4*)&part[(((size_t)s * BB + b) * KK + k) * CC + c0 + tc * 4] =
            make_float4(acc[i][0], acc[i][1], acc[i][2], acc[i][3]);
    }
}

// ---------------------------------------------------------------------------
// k_intra: sum ns partials, asum from tile-partials, subtract asum*cent,
// intra-normalize per (b,k), accumulate per-b sum of squares.
// ---------------------------------------------------------------------------
__global__ __launch_bounds__(256) void k_intra(const float* __restrict__ part, int ns,
                                               const float* __restrict__ asum_p,
                                               const float* __restrict__ cent,
                                               float* __restrict__ out,
                                               float* __restrict__ bsum) {
    int row = blockIdx.x;                          // b*KK + k
    int b = row >> 6, k = row & 63;
    int t = threadIdx.x;
    float v0 = 0.f, v1 = 0.f;
    for (int s2 = 0; s2 < ns; ++s2) {
        const float* p = part + (((size_t)s2 * BB + b) * KK + k) * CC;
        v0 += p[t];
        v1 += p[t + 256];
    }
    float as = 0.f;
#pragma unroll
    for (int i = 0; i < NT; ++i) as += asum_p[(size_t)row * NT + i];
    v0 -= as * cent[k * CC + t];
    v1 -= as * cent[k * CC + t + 256];
    float ssq = v0 * v0 + v1 * v1;
#pragma unroll
    for (int off = 32; off; off >>= 1) ssq += __shfl_down(ssq, off, 64);
    __shared__ float red[4];
    __shared__ float s_inv;
    if ((t & 63) == 0) red[t >> 6] = ssq;
    __syncthreads();
    if (t == 0) {
        float sm = red[0] + red[1] + red[2] + red[3];
        float inv = 1.f / fmaxf(sqrtf(sm), EPSF);
        s_inv = inv;
        atomicAdd(&bsum[b], sm * inv * inv);
    }
    __syncthreads();
    float inv = s_inv;
    out[(size_t)row * CC + t]       = v0 * inv;
    out[(size_t)row * CC + t + 256] = v1 * inv;
}

// ---------------------------------------------------------------------------
__global__ __launch_bounds__(256) void k_scale(float* __restrict__ out,
                                               const float* __restrict__ bsum) {
    int idx = blockIdx.x * 256 + threadIdx.x;      // B*K*C exact
    int b = idx >> 15;                             // K*C = 32768
    out[idx] *= 1.f / fmaxf(sqrtf(bsum[b]), EPSF);
}

// ---------------------------------------------------------------------------
extern "C" void kernel_launch(void* const* d_in, const int* in_sizes, int n_in,
                              void* d_out, int out_size, void* d_ws, size_t ws_size,
                              hipStream_t stream) {
    const float* x    = (const float*)d_in[0];   // [B,C,H,W]
    const float* cent = (const float*)d_in[1];   // [K,C]
    const float* w    = (const float*)d_in[2];   // [K,C]
    float* out = (float*)d_out;

    float* ws = (float*)d_ws;
    const size_t o_at   = 0;                      // B*N*K   = 3,276,800
    const size_t o_invn = 3276800;                // B*N     =    51,200
    const size_t o_ssq  = o_invn + 51200;         // B*2*N   =   102,400
    const size_t o_asum = o_ssq + 102400;         // B*K*NT  =    51,200
    const size_t o_bsum = o_asum + 51200;         // 64
    const size_t o_wt   = o_bsum + 64;            // C*K     =    32,768
    const size_t o_lp   = o_wt + 32768;           // 2*B*K*N = 6,553,600
    const size_t o_part = o_lp + 6553600;         // ns * B*K*C

    const size_t pelems = (size_t)BB * KK * CC;   // 1,048,576 per partial
    int ns = 0;
    const int cand[4] = {10, 5, 2, 1};
    for (int i = 0; i < 4; ++i) {
        if ((o_part + (size_t)cand[i] * pelems) * 4 <= ws_size) { ns = cand[i]; break; }
    }
    float* part = (ns > 0) ? (ws + o_part) : out;
    if (ns == 0) ns = 1;
    int nchunk = NPIX / ns;

    hipMemsetAsync(ws + o_bsum, 0, BB * sizeof(float), stream);

    k_wt   <<<dim3(8), 256, 0, stream>>>(w, ws + o_wt);
    k_gemm1<<<dim3(NT, 2, BB), 256, 0, stream>>>(x, ws + o_wt, ws + o_lp, ws + o_ssq);
    k_smax <<<dim3(NT, BB), 256, 0, stream>>>(ws + o_lp, ws + o_ssq, ws + o_at,
                                              ws + o_invn, ws + o_asum);
    k_vlad <<<dim3(4, ns, BB), 256, 0, stream>>>(ws + o_at, x, ws + o_invn, part, nchunk);
    k_intra<<<dim3(BB * KK), 256, 0, stream>>>(part, ns, ws + o_asum, cent, out, ws + o_bsum);
    k_scale<<<dim3((BB * KK * CC) / 256), 256, 0, stream>>>(out, ws + o_bsum);
}